// Round 10
// baseline (975.465 us; speedup 1.0000x reference)
//
#include <hip/hip_runtime.h>
#include <math.h>

#define NBATCH 4096
#define NH2 21
#define NK 77
#define NC 35
#define NIJ 441
#define Y_SIZE 33957
#define M_SIZE 5929
#define VOLOFF Y_SIZE          // vol[n] at out[VOLOFF + n] (temp, inside M region)
#define VSUM (Y_SIZE + 4096)   // volsum at out[VSUM] (temp, inside M region)
#define NPAIR 231              // upper-triangular (i<=j) pairs of 21
#define BLK 512                // contract block threads (8 waves)
#define NPB 8                  // n per contract block
#define GRID_B (NBATCH / NPB)  // 512 blocks

#define SZ_OMEGA  (NBATCH * NH2 * NH2)   // 1,806,336
#define SZ_PHI    (NBATCH * NK * NC)     // 11,038,720
#define SZ_METRIC (NBATCH * 7 * 7)       // 200,704

// ---------------- compile-time wedge structure constants ----------------
// C[a,b,c] nonzero iff pair_a, pair_b, triple_c partition {0..6}; value = perm
// sign. Exactly 6 (a,b) terms per c. MUST be a constexpr LOCAL in each kernel
// (round-3 finding). C[a,b,c]=C[b,a,c] => S symmetric in (i,j): only i<=j pairs.
// R5: never cap VGPRs below live set (spill -> 5x).
// R6: runtime-bound LDS loops in 1-wave kernel = serialized 120-cyc ds_reads.
// R7: LDS row strides sharing a factor with the bank-group period -> conflicts.
// R8: 2-barrier staged VALU loop plateaus ~27% VALUBusy (vmcnt(0) drain at
//     every s_barrier). Fixed in R9 by moving the contraction to bf16 MFMA.
// R9: eig (256 thr, 6 barriers + LDS-bounce reductions + per-j LDS broadcasts)
//     = 402 us on one CU. This round: single-wave, register v/w/p, shfl
//     reductions, readlane broadcasts, rcp-based Sturm.
struct WTab {
  int a[NC][6];
  int b[NC][6];
  int sg[NC][6];
};

constexpr WTab make_wtab() {
  WTab W{};
  int p0[21] = {}, p1[21] = {};
  int idx = 0;
  for (int x = 0; x < 7; ++x)
    for (int y = x + 1; y < 7; ++y) { p0[idx] = x; p1[idx] = y; ++idx; }
  int t0[35] = {}, t1[35] = {}, t2[35] = {};
  idx = 0;
  for (int x = 0; x < 7; ++x)
    for (int y = x + 1; y < 7; ++y)
      for (int z = y + 1; z < 7; ++z) { t0[idx] = x; t1[idx] = y; t2[idx] = z; ++idx; }
  int cnt[35] = {};
  for (int a = 0; a < 21; ++a)
    for (int b = 0; b < 21; ++b) {
      int pa0 = p0[a], pa1 = p1[a], pb0 = p0[b], pb1 = p1[b];
      if (pa0 == pb0 || pa0 == pb1 || pa1 == pb0 || pa1 == pb1) continue;
      bool used[7] = {};
      used[pa0] = true; used[pa1] = true; used[pb0] = true; used[pb1] = true;
      int tr[3] = {}; int k = 0;
      for (int x = 0; x < 7; ++x) if (!used[x]) tr[k++] = x;
      int c = -1;
      for (int cc = 0; cc < 35; ++cc)
        if (t0[cc] == tr[0] && t1[cc] == tr[1] && t2[cc] == tr[2]) { c = cc; break; }
      int perm[7] = {pa0, pa1, pb0, pb1, tr[0], tr[1], tr[2]};
      int inv = 0;
      for (int i = 0; i < 7; ++i)
        for (int j = i + 1; j < 7; ++j)
          if (perm[i] > perm[j]) ++inv;
      W.a[c][cnt[c]] = a; W.b[c][cnt[c]] = b; W.sg[c][cnt[c]] = (inv & 1) ? -1 : 1;
      ++cnt[c];
    }
  return W;
}

__device__ __forceinline__ int trioff(int i) { return 21 * i - (i * (i - 1)) / 2; }

// fp32 -> bf16 (RNE), returns low 16 bits
__device__ __forceinline__ unsigned f2bf(float x) {
  union { float f; unsigned u; } v; v.f = x;
  return ((v.u + 0x7FFFu + ((v.u >> 16) & 1u)) >> 16) & 0xFFFFu;
}

typedef float f32x4 __attribute__((ext_vector_type(4)));
typedef short s16x8 __attribute__((ext_vector_type(8)));

// ---------------- kernel A: vol[n] = sqrt(|det(metric_n)|), + sum ----------------
__global__ __launch_bounds__(256) void vol_kernel(const float* __restrict__ metric,
                                                  float* __restrict__ out) {
  const int n = blockIdx.x * 256 + threadIdx.x;
  double a[7][7];
#pragma unroll
  for (int r = 0; r < 7; ++r)
#pragma unroll
    for (int c = 0; c < 7; ++c) a[r][c] = (double)metric[n * 49 + r * 7 + c];

  double det = 1.0;
#pragma unroll
  for (int k = 0; k < 7; ++k) {
#pragma unroll
    for (int r = k + 1; r < 7; ++r) {   // bubble max |pivot| into row k
      bool sw = fabs(a[r][k]) > fabs(a[k][k]);
#pragma unroll
      for (int c = k; c < 7; ++c) {
        double u = a[k][c], v = a[r][c];
        a[k][c] = sw ? v : u;
        a[r][c] = sw ? u : v;
      }
    }
    det *= a[k][k];
    double inv = (a[k][k] != 0.0) ? 1.0 / a[k][k] : 0.0;
#pragma unroll
    for (int r = k + 1; r < 7; ++r) {
      double f = a[r][k] * inv;
#pragma unroll
      for (int c = k + 1; c < 7; ++c) a[r][c] -= f * a[k][c];
    }
  }
  float vol = (float)sqrt(fabs(det));
  out[VOLOFF + n] = vol;

  float s = vol;
#pragma unroll
  for (int off = 32; off > 0; off >>= 1) s += __shfl_down(s, off, 64);
  __shared__ float partial[4];
  const int lane = threadIdx.x & 63, wv = threadIdx.x >> 6;
  if (lane == 0) partial[wv] = s;
  __syncthreads();
  if (threadIdx.x == 0)
    atomicAdd(out + VSUM, partial[0] + partial[1] + partial[2] + partial[3]);
}

// ---------------- kernel B: MFMA contract (unchanged from R9) ----------------
__global__ __launch_bounds__(BLK) void contract_kernel(const float* __restrict__ omega,
                                                       const float* __restrict__ Phi,
                                                       float* __restrict__ out) {
  constexpr WTab W = make_wtab();
  __shared__ __align__(16) short ldsD[256 * 80];  // D rows, stride 80 bf16
  __shared__ __align__(16) short ldsP[80 * 80];   // PW^T rows [q][k], stride 80
  __shared__ __align__(16) float ldsO[NH2 * 28];  // omega rows, stride 28 fp32

  const int t = threadIdx.x;
  const int lane = t & 63;
  const int wv = t >> 6;        // 0..7
  const int quad = lane >> 4;   // 0..3
  const int col = lane & 15;    // m for A-frags, q for B-frags, col for C
  const int n0 = blockIdx.x * NPB;

  for (int f = t; f < 256 * 40; f += BLK) ((int*)ldsD)[f] = 0;
  for (int f = t; f < 80 * 40; f += BLK) ((int*)ldsP)[f] = 0;

  const bool roleA = (t < NPAIR);
  const bool roleB = (t >= 256) && (t < 256 + NPAIR);
  int pi = 0, pj = 0;
  {
    const int p = roleA ? t : (roleB ? (t - 256) : 0);
    int i = 0;
    while (i < 20 && trioff(i + 1) <= p) ++i;
    pi = i;
    pj = p - trioff(i) + i;
  }

  float rA = 0.0f, rB[6], rvn;
  {
    const float* om = omega + n0 * 441;
    const float* ph = Phi + n0 * 2695;
    if (t < 441) rA = om[t];
#pragma unroll
    for (int j = 0; j < 6; ++j) {
      const int e = t + j * BLK;
      rB[j] = (e < 2695) ? ph[e] : 0.0f;
    }
    rvn = out[VOLOFF + n0];
  }

  f32x4 acc[2][5];
#pragma unroll
  for (int mi = 0; mi < 2; ++mi)
#pragma unroll
    for (int nt = 0; nt < 5; ++nt) acc[mi][nt] = (f32x4){0.f, 0.f, 0.f, 0.f};

  for (int it = 0; it < NPB; ++it) {
    __syncthreads();

    if (t < 441) ldsO[(t / 21) * 28 + (t % 21)] = rA;
    {
      const float vn = rvn;
#pragma unroll
      for (int j = 0; j < 6; ++j) {
        const int e = t + j * BLK;
        if (e < 2695) {
          const int q = e / 35, c = e % 35;
          ldsP[q * 80 + c] = (short)f2bf(vn * rB[j]);
        }
      }
    }
    __syncthreads();

    if (it + 1 < NPB) {
      const int n1 = n0 + it + 1;
      const float* om2 = omega + n1 * 441;
      const float* ph2 = Phi + n1 * 2695;
      if (t < 441) rA = om2[t];
#pragma unroll
      for (int j = 0; j < 6; ++j) {
        const int e = t + j * BLK;
        if (e < 2695) rB[j] = ph2[e];
      }
      rvn = out[VOLOFF + n1];
    }

    if (roleA || roleB) {
      float wi[21], wj[21];
      const float* oi = ldsO + pi * 28;
      const float* oj = ldsO + pj * 28;
#pragma unroll
      for (int a = 0; a < 20; a += 4) {
        float4 v = *(const float4*)(oi + a);
        wi[a] = v.x; wi[a + 1] = v.y; wi[a + 2] = v.z; wi[a + 3] = v.w;
        float4 u = *(const float4*)(oj + a);
        wj[a] = u.x; wj[a + 1] = u.y; wj[a + 2] = u.z; wj[a + 3] = u.w;
      }
      wi[20] = oi[20]; wj[20] = oj[20];

      if (roleA) {
        float d[18];
#pragma unroll
        for (int c = 0; c < 18; ++c) {
          float dd = 0.0f;
#pragma unroll
          for (int u = 0; u < 6; ++u)
            dd = fmaf((W.sg[c][u] > 0) ? wi[W.a[c][u]] : -wi[W.a[c][u]], wj[W.b[c][u]], dd);
          d[c] = dd;
        }
        int* Drow = (int*)ldsD + t * 40;
#pragma unroll
        for (int k2 = 0; k2 < 9; ++k2)
          Drow[k2] = (int)(f2bf(d[2 * k2]) | (f2bf(d[2 * k2 + 1]) << 16));
      } else {
        float d[17];
#pragma unroll
        for (int c = 18; c < 35; ++c) {
          float dd = 0.0f;
#pragma unroll
          for (int u = 0; u < 6; ++u)
            dd = fmaf((W.sg[c][u] > 0) ? wi[W.a[c][u]] : -wi[W.a[c][u]], wj[W.b[c][u]], dd);
          d[c - 18] = dd;
        }
        int* Drow = (int*)ldsD + (t - 256) * 40;
#pragma unroll
        for (int k2 = 0; k2 < 8; ++k2)
          Drow[9 + k2] = (int)(f2bf(d[2 * k2]) | (f2bf(d[2 * k2 + 1]) << 16));
        Drow[17] = (int)f2bf(d[16]);
      }
    }
    __syncthreads();

#pragma unroll
    for (int s = 0; s < 2; ++s) {
      const int kof = s * 32 + quad * 8;
      s16x8 a0 = *(const s16x8*)(ldsD + ((wv * 2 + 0) * 16 + col) * 80 + kof);
      s16x8 a1 = *(const s16x8*)(ldsD + ((wv * 2 + 1) * 16 + col) * 80 + kof);
      s16x8 b[5];
#pragma unroll
      for (int nt = 0; nt < 5; ++nt)
        b[nt] = *(const s16x8*)(ldsP + (nt * 16 + col) * 80 + kof);
#pragma unroll
      for (int nt = 0; nt < 5; ++nt) {
        acc[0][nt] = __builtin_amdgcn_mfma_f32_16x16x32_bf16(a0, b[nt], acc[0][nt], 0, 0, 0);
        acc[1][nt] = __builtin_amdgcn_mfma_f32_16x16x32_bf16(a1, b[nt], acc[1][nt], 0, 0, 0);
      }
    }
  }

#pragma unroll
  for (int mi = 0; mi < 2; ++mi) {
    const int mt = wv * 2 + mi;
#pragma unroll
    for (int r = 0; r < 4; ++r) {
      const int m = mt * 16 + quad * 4 + r;
      if (m < NPAIR) {
        int i = 0;
        while (i < 20 && trioff(i + 1) <= m) ++i;
        const int jj = m - trioff(i) + i;
        const int base = (i * 21 + jj) * 77;
#pragma unroll
        for (int nt = 0; nt < 5; ++nt) {
          const int q = nt * 16 + col;
          if (q < 77) atomicAdd(&out[base + q], acc[mi][nt][r]);
        }
      }
    }
  }
}

// ---------------- kernel C1: finalize Y from upper-triangular Sraw -------------
__global__ __launch_bounds__(256) void finalize_y(float* __restrict__ out) {
  const int e = blockIdx.x * 256 + threadIdx.x;
  if (e >= NPAIR * NK) return;
  const int p = e / NK, k = e % NK;
  int i = 0;
  while (i < 20 && trioff(i + 1) <= p) ++i;
  const int j = p - trioff(i) + i;
  const float inv = 1.0f / out[VSUM];
  const float v = out[(i * 21 + j) * NK + k] * inv;
  out[(i * 21 + j) * NK + k] = v;
  if (j != i) out[(j * 21 + i) * NK + k] = -v;
}

// ---------------- kernel C2: M[k,l] = sum_ij Y_ij,k Y_ij,l ----------------
__global__ __launch_bounds__(256) void gram_kernel(const float* __restrict__ Y,
                                                   float* __restrict__ Mout) {
  const int e = blockIdx.x * 256 + threadIdx.x;
  if (e >= M_SIZE) return;
  const int k = e / NK, l = e % NK;
  float acc = 0.0f;
  for (int ij = 0; ij < NIJ; ++ij)
    acc = fmaf(Y[ij * NK + k], Y[ij * NK + l], acc);
  Mout[e] = acc;
}

// ---------------- kernel D: eigvalsh(M) — SINGLE WAVE, zero-barrier dataflow ---
// Lane l owns rows l and 64+l (l<13). v, w, p live in registers; reductions are
// 6-step shfl_xor butterflies; per-j broadcasts are shfl (VALU) not LDS reads.
// One cheap 1-wave __syncthreads per k-step for cross-lane A visibility.
// Masking invariants (validated R7/R9): v,w zero outside window k+1..76 =>
// full-range rank-2 update is a no-op on frozen rows/cols. Second-row writes
// guarded by (t<13) to avoid same-address write races.
// Sturm bisection: native rcp (sign-safe), 34 iters; 77 chains on 64 lanes.
__global__ __launch_bounds__(64) void eig_kernel(const float* __restrict__ Min,
                                                 float* __restrict__ eout) {
  __shared__ float A[77][79];   // stride 79: (15*lane + j) % 32 -> 2-way max (free)
  __shared__ float dsh[77], e2sh[77], esh[77];
  const int t = threadIdx.x;    // 0..63
  const bool two = (t < 13);    // lane also owns row 64+t
  const int rb = two ? (64 + t) : 64;  // clamped: reads harmless, writes guarded

  for (int f = t; f < M_SIZE; f += 64) A[f / 77][f % 77] = Min[f];
  __syncthreads();

  for (int k = 0; k < 75; ++k) {
    // row k (== column k, symmetric): element j owned by lane j / j-64
    const float xa = A[k][t];
    const float xb = two ? A[k][64 + t] : 0.0f;
    const bool actA = (t > k);
    const bool actB = two && (64 + t > k);   // true for k<64+t; guards small-t/large-k
    const float sxa = actA ? xa : 0.0f;
    const float sxb = actB ? xb : 0.0f;

    float s2 = sxa * sxa + sxb * sxb;
#pragma unroll
    for (int off = 1; off < 64; off <<= 1) s2 += __shfl_xor(s2, off, 64);
    const float sigma2 = s2;

    const float x1 = (k + 1 < 64) ? __shfl(xa, k + 1, 64) : __shfl(xb, k - 63, 64);

    if (sigma2 < 1e-26f) {      // uniform branch (all lanes agree)
      if (t == 0) esh[k] = 0.0f;
      __syncthreads();
      continue;
    }
    const float sigma = sqrtf(sigma2);
    const float alpha = (x1 >= 0.0f) ? -sigma : sigma;
    const float beta = 1.0f / (sigma2 - alpha * x1);   // = 2 / (v^T v)
    if (t == 0) esh[k] = alpha;

    // v in registers (masked to window)
    const float va = actA ? ((t == k + 1) ? (x1 - alpha) : xa) : 0.0f;
    const float vb = actB ? ((64 + t == k + 1) ? (x1 - alpha) : xb) : 0.0f;

    // p = beta * A v  (rows t and 64+t); vj broadcast via shfl (reg, no LDS)
    float pa0 = 0.f, pa1 = 0.f, pb0 = 0.f, pb1 = 0.f;
#pragma unroll
    for (int j = 0; j < 77; j += 2) {
      const float vj0 = (j < 64) ? __shfl(va, j, 64) : __shfl(vb, j - 64, 64);
      pa0 = fmaf(A[t][j], vj0, pa0);
      pb0 = fmaf(A[rb][j], vj0, pb0);
      if (j + 1 < 77) {
        const float vj1 = (j + 1 < 64) ? __shfl(va, j + 1, 64) : __shfl(vb, j - 63, 64);
        pa1 = fmaf(A[t][j + 1], vj1, pa1);
        pb1 = fmaf(A[rb][j + 1], vj1, pb1);
      }
    }
    const float pa = beta * (pa0 + pa1);
    const float pb = beta * (pb0 + pb1);

    // K = p.v  (masked automatically: va/vb zero outside window)
    float k2 = pa * va + pb * vb;
#pragma unroll
    for (int off = 1; off < 64; off <<= 1) k2 += __shfl_xor(k2, off, 64);
    const float hb = 0.5f * beta * k2;

    const float wa = actA ? (pa - hb * va) : 0.0f;
    const float wb = actB ? (pb - hb * vb) : 0.0f;

    // A -= v w^T + w v^T  (full range; no-op on frozen rows/cols by masking)
#pragma unroll
    for (int j = 0; j < 77; ++j) {
      const float vj = (j < 64) ? __shfl(va, j, 64) : __shfl(vb, j - 64, 64);
      const float wj = (j < 64) ? __shfl(wa, j, 64) : __shfl(wb, j - 64, 64);
      A[t][j] -= va * wj + wa * vj;
      if (two) A[64 + t][j] -= vb * wj + wb * vj;
    }
    __syncthreads();   // 1-wave barrier: just the lgkm drain, cheap
  }

  // gather tridiagonal
  if (t < 64) dsh[t] = A[t][t];
  if (two) dsh[64 + t] = A[64 + t][64 + t];
  if (t == 0) { esh[75] = A[76][75]; esh[76] = 0.0f; }
  __syncthreads();
  if (t < 64) e2sh[t] = esh[t] * esh[t];
  if (two) e2sh[64 + t] = esh[64 + t] * esh[64 + t];
  __syncthreads();

  // Gershgorin bounds via butterfly min/max over owned indices
  float lo_ = 1e30f, hi_ = -1e30f;
  {
    const int ia = t;
    float r = ((ia > 0) ? fabsf(esh[ia - 1]) : 0.0f) + ((ia < 76) ? fabsf(esh[ia]) : 0.0f);
    lo_ = dsh[ia] - r;
    hi_ = dsh[ia] + r;
    if (two) {
      const int ib = 64 + t;
      float r2 = fabsf(esh[ib - 1]) + ((ib < 76) ? fabsf(esh[ib]) : 0.0f);
      lo_ = fminf(lo_, dsh[ib] - r2);
      hi_ = fmaxf(hi_, dsh[ib] + r2);
    }
  }
#pragma unroll
  for (int off = 1; off < 64; off <<= 1) {
    lo_ = fminf(lo_, __shfl_xor(lo_, off, 64));
    hi_ = fmaxf(hi_, __shfl_xor(hi_, off, 64));
  }
  const float span = hi_ - lo_;
  const float glo = lo_ - 0.001f * span - 1e-6f;
  const float ghi = hi_ + 0.001f * span + 1e-6f;

  // bisection: lane t runs chains for idx t and (t<13) 64+t, interleaved
  float lo0 = glo, hi0 = ghi, lo1 = glo, hi1 = ghi;
  const int idx1 = 64 + t;
  for (int it = 0; it < 34; ++it) {
    const float m0 = 0.5f * (lo0 + hi0);
    const float m1 = 0.5f * (lo1 + hi1);
    float q0 = dsh[0] - m0;
    float q1 = dsh[0] - m1;
    int c0 = (q0 < 0.0f);
    int c1 = (q1 < 0.0f);
#pragma unroll 7
    for (int i = 1; i < 77; ++i) {
      const float di = dsh[i];
      const float e2 = e2sh[i - 1];
      q0 = (fabsf(q0) < 1e-30f) ? -1e-30f : q0;
      q1 = (fabsf(q1) < 1e-30f) ? -1e-30f : q1;
      q0 = di - m0 - e2 * __builtin_amdgcn_rcpf(q0);
      q1 = di - m1 - e2 * __builtin_amdgcn_rcpf(q1);
      c0 += (q0 < 0.0f);
      c1 += (q1 < 0.0f);
    }
    if (c0 > t) hi0 = m0; else lo0 = m0;
    if (c1 > idx1) hi1 = m1; else lo1 = m1;
  }
  eout[76 - t] = 0.5f * (lo0 + hi0);            // descending
  if (two) eout[76 - idx1] = 0.5f * (lo1 + hi1);
}

// ---------------- launch ----------------
extern "C" void kernel_launch(void* const* d_in, const int* in_sizes, int n_in,
                              void* d_out, int out_size, void* d_ws, size_t ws_size,
                              hipStream_t stream) {
  const float* omega  = (const float*)d_in[0];
  const float* Phi    = (const float*)d_in[1];
  const float* metric = (const float*)d_in[2];
  for (int q = 0; q < n_in && q < 3; ++q) {
    if (in_sizes[q] == SZ_OMEGA)       omega  = (const float*)d_in[q];
    else if (in_sizes[q] == SZ_PHI)    Phi    = (const float*)d_in[q];
    else if (in_sizes[q] == SZ_METRIC) metric = (const float*)d_in[q];
  }

  float* out = (float*)d_out;

  // All scratch inside d_out (d_ws unused):
  //   out[0 .. Y_SIZE)            : Sraw accumulator -> finalized Y
  //   out[VOLOFF .. VOLOFF+4096)  : vol[n] (temp, overwritten by gram's M)
  //   out[VSUM]                   : volsum (temp, overwritten by gram's M)
  hipMemsetAsync(d_out, 0, (size_t)out_size * sizeof(float), stream);

  hipLaunchKernelGGL(vol_kernel, dim3(NBATCH / 256), dim3(256), 0, stream, metric, out);
  hipLaunchKernelGGL(contract_kernel, dim3(GRID_B), dim3(BLK), 0, stream,
                     omega, Phi, out);
  hipLaunchKernelGGL(finalize_y, dim3((NPAIR * NK + 255) / 256), dim3(256), 0, stream,
                     out);
  hipLaunchKernelGGL(gram_kernel, dim3((M_SIZE + 255) / 256), dim3(256), 0, stream,
                     out, out + Y_SIZE);
  hipLaunchKernelGGL(eig_kernel, dim3(1), dim3(64), 0, stream,
                     out + Y_SIZE, out + Y_SIZE + M_SIZE);
}

// Round 11
// 482.154 us; speedup vs baseline: 2.0231x; 2.0231x over previous
//
#include <hip/hip_runtime.h>
#include <math.h>

#define NBATCH 4096
#define NH2 21
#define NK 77
#define NC 35
#define NIJ 441
#define Y_SIZE 33957
#define M_SIZE 5929
#define VOLOFF Y_SIZE          // vol[n] at out[VOLOFF + n] (temp, inside M region)
#define VSUM (Y_SIZE + 4096)   // volsum at out[VSUM] (temp, inside M region)
#define NPAIR 231              // upper-triangular (i<=j) pairs of 21
#define BLK 512                // contract block threads (8 waves)
#define NPB 8                  // n per contract block
#define GRID_B (NBATCH / NPB)  // 512 blocks
#define EIGT 320               // eig block: 5 waves, 308 active in quad phases

#define SZ_OMEGA  (NBATCH * NH2 * NH2)   // 1,806,336
#define SZ_PHI    (NBATCH * NK * NC)     // 11,038,720
#define SZ_METRIC (NBATCH * 7 * 7)       // 200,704

// ---------------- compile-time wedge structure constants ----------------
// C[a,b,c] nonzero iff pair_a, pair_b, triple_c partition {0..6}; value = perm
// sign. Exactly 6 (a,b) terms per c. MUST be a constexpr LOCAL in each kernel
// (round-3 finding). C[a,b,c]=C[b,a,c] => S symmetric in (i,j): only i<=j pairs.
// R5: never cap VGPRs below live set (spill -> 5x).
// R6/R9/R10 LAW: single-block eig time ~ 1/(active waves). 1 wave = issue-
//   starved (713-800 us); ~1.2 waves = 402; this round targets ~4.8 waves.
// R7: LDS strides sharing a factor with the bank-group period -> conflicts.
// R8: 2-barrier staged VALU loop plateaus ~27% VALUBusy -> moved to MFMA (R9).
struct WTab {
  int a[NC][6];
  int b[NC][6];
  int sg[NC][6];
};

constexpr WTab make_wtab() {
  WTab W{};
  int p0[21] = {}, p1[21] = {};
  int idx = 0;
  for (int x = 0; x < 7; ++x)
    for (int y = x + 1; y < 7; ++y) { p0[idx] = x; p1[idx] = y; ++idx; }
  int t0[35] = {}, t1[35] = {}, t2[35] = {};
  idx = 0;
  for (int x = 0; x < 7; ++x)
    for (int y = x + 1; y < 7; ++y)
      for (int z = y + 1; z < 7; ++z) { t0[idx] = x; t1[idx] = y; t2[idx] = z; ++idx; }
  int cnt[35] = {};
  for (int a = 0; a < 21; ++a)
    for (int b = 0; b < 21; ++b) {
      int pa0 = p0[a], pa1 = p1[a], pb0 = p0[b], pb1 = p1[b];
      if (pa0 == pb0 || pa0 == pb1 || pa1 == pb0 || pa1 == pb1) continue;
      bool used[7] = {};
      used[pa0] = true; used[pa1] = true; used[pb0] = true; used[pb1] = true;
      int tr[3] = {}; int k = 0;
      for (int x = 0; x < 7; ++x) if (!used[x]) tr[k++] = x;
      int c = -1;
      for (int cc = 0; cc < 35; ++cc)
        if (t0[cc] == tr[0] && t1[cc] == tr[1] && t2[cc] == tr[2]) { c = cc; break; }
      int perm[7] = {pa0, pa1, pb0, pb1, tr[0], tr[1], tr[2]};
      int inv = 0;
      for (int i = 0; i < 7; ++i)
        for (int j = i + 1; j < 7; ++j)
          if (perm[i] > perm[j]) ++inv;
      W.a[c][cnt[c]] = a; W.b[c][cnt[c]] = b; W.sg[c][cnt[c]] = (inv & 1) ? -1 : 1;
      ++cnt[c];
    }
  return W;
}

__device__ __forceinline__ int trioff(int i) { return 21 * i - (i * (i - 1)) / 2; }

// fp32 -> bf16 (RNE), returns low 16 bits
__device__ __forceinline__ unsigned f2bf(float x) {
  union { float f; unsigned u; } v; v.f = x;
  return ((v.u + 0x7FFFu + ((v.u >> 16) & 1u)) >> 16) & 0xFFFFu;
}

typedef float f32x4 __attribute__((ext_vector_type(4)));
typedef short s16x8 __attribute__((ext_vector_type(8)));

// ---------------- kernel A: vol[n] = sqrt(|det(metric_n)|), + sum ----------------
__global__ __launch_bounds__(256) void vol_kernel(const float* __restrict__ metric,
                                                  float* __restrict__ out) {
  const int n = blockIdx.x * 256 + threadIdx.x;
  double a[7][7];
#pragma unroll
  for (int r = 0; r < 7; ++r)
#pragma unroll
    for (int c = 0; c < 7; ++c) a[r][c] = (double)metric[n * 49 + r * 7 + c];

  double det = 1.0;
#pragma unroll
  for (int k = 0; k < 7; ++k) {
#pragma unroll
    for (int r = k + 1; r < 7; ++r) {
      bool sw = fabs(a[r][k]) > fabs(a[k][k]);
#pragma unroll
      for (int c = k; c < 7; ++c) {
        double u = a[k][c], v = a[r][c];
        a[k][c] = sw ? v : u;
        a[r][c] = sw ? u : v;
      }
    }
    det *= a[k][k];
    double inv = (a[k][k] != 0.0) ? 1.0 / a[k][k] : 0.0;
#pragma unroll
    for (int r = k + 1; r < 7; ++r) {
      double f = a[r][k] * inv;
#pragma unroll
      for (int c = k + 1; c < 7; ++c) a[r][c] -= f * a[k][c];
    }
  }
  float vol = (float)sqrt(fabs(det));
  out[VOLOFF + n] = vol;

  float s = vol;
#pragma unroll
  for (int off = 32; off > 0; off >>= 1) s += __shfl_down(s, off, 64);
  __shared__ float partial[4];
  const int lane = threadIdx.x & 63, wv = threadIdx.x >> 6;
  if (lane == 0) partial[wv] = s;
  __syncthreads();
  if (threadIdx.x == 0)
    atomicAdd(out + VSUM, partial[0] + partial[1] + partial[2] + partial[3]);
}

// ---------------- kernel B: MFMA contract (unchanged from R9) ----------------
__global__ __launch_bounds__(BLK) void contract_kernel(const float* __restrict__ omega,
                                                       const float* __restrict__ Phi,
                                                       float* __restrict__ out) {
  constexpr WTab W = make_wtab();
  __shared__ __align__(16) short ldsD[256 * 80];  // D rows, stride 80 bf16
  __shared__ __align__(16) short ldsP[80 * 80];   // PW^T rows [q][k], stride 80
  __shared__ __align__(16) float ldsO[NH2 * 28];  // omega rows, stride 28 fp32

  const int t = threadIdx.x;
  const int lane = t & 63;
  const int wv = t >> 6;
  const int quad = lane >> 4;
  const int col = lane & 15;
  const int n0 = blockIdx.x * NPB;

  for (int f = t; f < 256 * 40; f += BLK) ((int*)ldsD)[f] = 0;
  for (int f = t; f < 80 * 40; f += BLK) ((int*)ldsP)[f] = 0;

  const bool roleA = (t < NPAIR);
  const bool roleB = (t >= 256) && (t < 256 + NPAIR);
  int pi = 0, pj = 0;
  {
    const int p = roleA ? t : (roleB ? (t - 256) : 0);
    int i = 0;
    while (i < 20 && trioff(i + 1) <= p) ++i;
    pi = i;
    pj = p - trioff(i) + i;
  }

  float rA = 0.0f, rB[6], rvn;
  {
    const float* om = omega + n0 * 441;
    const float* ph = Phi + n0 * 2695;
    if (t < 441) rA = om[t];
#pragma unroll
    for (int j = 0; j < 6; ++j) {
      const int e = t + j * BLK;
      rB[j] = (e < 2695) ? ph[e] : 0.0f;
    }
    rvn = out[VOLOFF + n0];
  }

  f32x4 acc[2][5];
#pragma unroll
  for (int mi = 0; mi < 2; ++mi)
#pragma unroll
    for (int nt = 0; nt < 5; ++nt) acc[mi][nt] = (f32x4){0.f, 0.f, 0.f, 0.f};

  for (int it = 0; it < NPB; ++it) {
    __syncthreads();

    if (t < 441) ldsO[(t / 21) * 28 + (t % 21)] = rA;
    {
      const float vn = rvn;
#pragma unroll
      for (int j = 0; j < 6; ++j) {
        const int e = t + j * BLK;
        if (e < 2695) {
          const int q = e / 35, c = e % 35;
          ldsP[q * 80 + c] = (short)f2bf(vn * rB[j]);
        }
      }
    }
    __syncthreads();

    if (it + 1 < NPB) {
      const int n1 = n0 + it + 1;
      const float* om2 = omega + n1 * 441;
      const float* ph2 = Phi + n1 * 2695;
      if (t < 441) rA = om2[t];
#pragma unroll
      for (int j = 0; j < 6; ++j) {
        const int e = t + j * BLK;
        if (e < 2695) rB[j] = ph2[e];
      }
      rvn = out[VOLOFF + n1];
    }

    if (roleA || roleB) {
      float wi[21], wj[21];
      const float* oi = ldsO + pi * 28;
      const float* oj = ldsO + pj * 28;
#pragma unroll
      for (int a = 0; a < 20; a += 4) {
        float4 v = *(const float4*)(oi + a);
        wi[a] = v.x; wi[a + 1] = v.y; wi[a + 2] = v.z; wi[a + 3] = v.w;
        float4 u = *(const float4*)(oj + a);
        wj[a] = u.x; wj[a + 1] = u.y; wj[a + 2] = u.z; wj[a + 3] = u.w;
      }
      wi[20] = oi[20]; wj[20] = oj[20];

      if (roleA) {
        float d[18];
#pragma unroll
        for (int c = 0; c < 18; ++c) {
          float dd = 0.0f;
#pragma unroll
          for (int u = 0; u < 6; ++u)
            dd = fmaf((W.sg[c][u] > 0) ? wi[W.a[c][u]] : -wi[W.a[c][u]], wj[W.b[c][u]], dd);
          d[c] = dd;
        }
        int* Drow = (int*)ldsD + t * 40;
#pragma unroll
        for (int k2 = 0; k2 < 9; ++k2)
          Drow[k2] = (int)(f2bf(d[2 * k2]) | (f2bf(d[2 * k2 + 1]) << 16));
      } else {
        float d[17];
#pragma unroll
        for (int c = 18; c < 35; ++c) {
          float dd = 0.0f;
#pragma unroll
          for (int u = 0; u < 6; ++u)
            dd = fmaf((W.sg[c][u] > 0) ? wi[W.a[c][u]] : -wi[W.a[c][u]], wj[W.b[c][u]], dd);
          d[c - 18] = dd;
        }
        int* Drow = (int*)ldsD + (t - 256) * 40;
#pragma unroll
        for (int k2 = 0; k2 < 8; ++k2)
          Drow[9 + k2] = (int)(f2bf(d[2 * k2]) | (f2bf(d[2 * k2 + 1]) << 16));
        Drow[17] = (int)f2bf(d[16]);
      }
    }
    __syncthreads();

#pragma unroll
    for (int s = 0; s < 2; ++s) {
      const int kof = s * 32 + quad * 8;
      s16x8 a0 = *(const s16x8*)(ldsD + ((wv * 2 + 0) * 16 + col) * 80 + kof);
      s16x8 a1 = *(const s16x8*)(ldsD + ((wv * 2 + 1) * 16 + col) * 80 + kof);
      s16x8 b[5];
#pragma unroll
      for (int nt = 0; nt < 5; ++nt)
        b[nt] = *(const s16x8*)(ldsP + (nt * 16 + col) * 80 + kof);
#pragma unroll
      for (int nt = 0; nt < 5; ++nt) {
        acc[0][nt] = __builtin_amdgcn_mfma_f32_16x16x32_bf16(a0, b[nt], acc[0][nt], 0, 0, 0);
        acc[1][nt] = __builtin_amdgcn_mfma_f32_16x16x32_bf16(a1, b[nt], acc[1][nt], 0, 0, 0);
      }
    }
  }

#pragma unroll
  for (int mi = 0; mi < 2; ++mi) {
    const int mt = wv * 2 + mi;
#pragma unroll
    for (int r = 0; r < 4; ++r) {
      const int m = mt * 16 + quad * 4 + r;
      if (m < NPAIR) {
        int i = 0;
        while (i < 20 && trioff(i + 1) <= m) ++i;
        const int jj = m - trioff(i) + i;
        const int base = (i * 21 + jj) * 77;
#pragma unroll
        for (int nt = 0; nt < 5; ++nt) {
          const int q = nt * 16 + col;
          if (q < 77) atomicAdd(&out[base + q], acc[mi][nt][r]);
        }
      }
    }
  }
}

// ---------------- kernel C1: finalize Y from upper-triangular Sraw -------------
__global__ __launch_bounds__(256) void finalize_y(float* __restrict__ out) {
  const int e = blockIdx.x * 256 + threadIdx.x;
  if (e >= NPAIR * NK) return;
  const int p = e / NK, k = e % NK;
  int i = 0;
  while (i < 20 && trioff(i + 1) <= p) ++i;
  const int j = p - trioff(i) + i;
  const float inv = 1.0f / out[VSUM];
  const float v = out[(i * 21 + j) * NK + k] * inv;
  out[(i * 21 + j) * NK + k] = v;
  if (j != i) out[(j * 21 + i) * NK + k] = -v;
}

// ---------------- kernel C2: M[k,l] = sum_ij Y_ij,k Y_ij,l ----------------
__global__ __launch_bounds__(256) void gram_kernel(const float* __restrict__ Y,
                                                   float* __restrict__ Mout) {
  const int e = blockIdx.x * 256 + threadIdx.x;
  if (e >= M_SIZE) return;
  const int k = e / NK, l = e % NK;
  float acc = 0.0f;
  for (int ij = 0; ij < NIJ; ++ij)
    acc = fmaf(Y[ij * NK + k], Y[ij * NK + l], acc);
  Mout[e] = acc;
}

// ---------------- kernel D: eigvalsh(M) — quad-parallel, 5 waves ----------------
// t = 4i+q: row i (0..79), column-quarter q (20 cols). 308 active lanes in the
// matvec and rank-2 update (~4.8 waves). v,w interleaved in vw[] so quarter
// reads are float4 broadcasts; quad combine via shfl_xor(1),(2). A stride 80
// (aligned float4; group (4i+5q)%8 evenly spread = baseline). Rows 77..79 and
// cols 77..79 zero-padded; vw pads zero => full-range update exact on pads.
__global__ __launch_bounds__(EIGT) void eig_kernel(const float* __restrict__ Min,
                                                   float* __restrict__ eout) {
  __shared__ __align__(16) float A[80 * 80];   // stride 80, rows 77..79 pad
  __shared__ __align__(16) float vw[160];      // (v_i, w_i) pairs, pads zero
  __shared__ float esh[77], dsh[80], e2sh[80];
  __shared__ float red[5], red2[5];
  const int t = threadIdx.x;
  const int lane = t & 63, wv = t >> 6;
  const int qi = t >> 2;   // 0..79
  const int qq = t & 3;
  const bool actq = (qi < 77);

  for (int f = t; f < 80 * 80; f += EIGT) A[f] = 0.0f;
  if (t < 160) vw[t] = 0.0f;
  __syncthreads();
  for (int f = t; f < M_SIZE; f += EIGT) A[(f / 77) * 80 + (f % 77)] = Min[f];
  __syncthreads();

  for (int k = 0; k < 75; ++k) {
    // sigma2 over row k (== column k, A symmetric); lanes t<77 own element t
    const float xa = (t < 77) ? A[k * 80 + t] : 0.0f;
    float part = (t < 77 && t > k) ? xa * xa : 0.0f;
#pragma unroll
    for (int off = 1; off < 64; off <<= 1) part += __shfl_xor(part, off, 64);
    if (lane == 0) red[wv] = part;
    __syncthreads();
    const float sigma2 = red[0] + red[1] + red[2] + red[3] + red[4];
    const float x1 = A[k * 80 + k + 1];   // wave-uniform broadcast

    if (sigma2 < 1e-26f) {                // block-uniform branch
      if (t == 0) esh[k] = 0.0f;
      __syncthreads();
      continue;
    }
    const float sigma = sqrtf(sigma2);
    const float alpha = (x1 >= 0.0f) ? -sigma : sigma;
    const float beta = 1.0f / (sigma2 - alpha * x1);  // = 2 / (v^T v)

    if (t < 77)
      vw[2 * t] = (t > k) ? ((t == k + 1) ? (x1 - alpha) : xa) : 0.0f;
    if (t == 0) esh[k] = alpha;
    __syncthreads();

    // p_i = beta * (A v)_i ; quarter-dot then quad combine
    float p;
    {
      const float* Ar = A + qi * 80 + qq * 20;
      const float* vp = vw + qq * 40;     // same for all i -> broadcast reads
      float s0 = 0.f, s1 = 0.f;
#pragma unroll
      for (int m = 0; m < 5; ++m) {
        float4 av = *(const float4*)(Ar + 4 * m);
        float4 p0 = *(const float4*)(vp + 8 * m);      // v,w,v,w
        float4 p1 = *(const float4*)(vp + 8 * m + 4);
        s0 = fmaf(av.x, p0.x, s0);
        s1 = fmaf(av.y, p0.z, s1);
        s0 = fmaf(av.z, p1.x, s0);
        s1 = fmaf(av.w, p1.z, s1);
      }
      p = s0 + s1;
      p += __shfl_xor(p, 1, 64);
      p += __shfl_xor(p, 2, 64);          // all 4 quad lanes hold full p_i
      p *= beta;
    }

    // K = p . v
    float vi = 0.0f;
    if (qq == 0 && actq) vi = vw[2 * qi];
    float part2 = (qq == 0 && actq) ? p * vi : 0.0f;
#pragma unroll
    for (int off = 1; off < 64; off <<= 1) part2 += __shfl_xor(part2, off, 64);
    if (lane == 0) red2[wv] = part2;
    __syncthreads();
    const float K = red2[0] + red2[1] + red2[2] + red2[3] + red2[4];
    const float hb = 0.5f * beta * K;

    if (qq == 0 && actq)
      vw[2 * qi + 1] = (qi > k) ? (p - hb * vi) : 0.0f;   // w masked (critical)
    __syncthreads();

    // A -= v w^T + w v^T (full range; pads exact no-ops since vw pads zero)
    {
      const float2 vwi = *(const float2*)(vw + 2 * qi);  // v_i, w_i
      float* Ar = A + qi * 80 + qq * 20;
      const float* vp = vw + qq * 40;
#pragma unroll
      for (int m = 0; m < 5; ++m) {
        float4 av = *(const float4*)(Ar + 4 * m);
        float4 p0 = *(const float4*)(vp + 8 * m);
        float4 p1 = *(const float4*)(vp + 8 * m + 4);
        av.x -= vwi.x * p0.y + vwi.y * p0.x;
        av.y -= vwi.x * p0.w + vwi.y * p0.z;
        av.z -= vwi.x * p1.y + vwi.y * p1.x;
        av.w -= vwi.x * p1.w + vwi.y * p1.z;
        *(float4*)(Ar + 4 * m) = av;
      }
    }
    __syncthreads();
  }

  // tridiagonal gather
  if (t < 77) dsh[t] = A[t * 80 + t];
  if (t == 0) esh[75] = A[76 * 80 + 75];
  __syncthreads();
  if (t < 76) e2sh[t] = esh[t] * esh[t];

  // Gershgorin bounds (parallel reduce)
  float lo_ = 1e30f, hi_ = -1e30f;
  if (t < 77) {
    const float r = ((t > 0) ? fabsf(esh[t - 1]) : 0.0f) +
                    ((t < 76) ? fabsf(esh[t]) : 0.0f);
    lo_ = dsh[t] - r;
    hi_ = dsh[t] + r;
  }
#pragma unroll
  for (int off = 1; off < 64; off <<= 1) {
    lo_ = fminf(lo_, __shfl_xor(lo_, off, 64));
    hi_ = fmaxf(hi_, __shfl_xor(hi_, off, 64));
  }
  if (lane == 0) { red[wv] = lo_; red2[wv] = hi_; }
  __syncthreads();
  lo_ = fminf(fminf(red[0], red[1]), fminf(red[2], fminf(red[3], red[4])));
  hi_ = fmaxf(fmaxf(red2[0], red2[1]), fmaxf(red2[2], fmaxf(red2[3], red2[4])));
  const float span = hi_ - lo_;
  const float glo = lo_ - 0.001f * span - 1e-6f;
  const float ghi = hi_ + 0.001f * span + 1e-6f;

  // bisection via Sturm count (rcp validated R10), one eigenvalue per thread
  if (t < 77) {
    float lo = glo, hi = ghi;
    for (int it = 0; it < 38; ++it) {
      const float mid = 0.5f * (lo + hi);
      float q = dsh[0] - mid;
      int cnt = (q < 0.0f);
#pragma unroll 4
      for (int i = 1; i < 77; ++i) {
        q = (fabsf(q) < 1e-30f) ? -1e-30f : q;
        q = dsh[i] - mid - e2sh[i - 1] * __builtin_amdgcn_rcpf(q);
        cnt += (q < 0.0f);
      }
      if (cnt > t) hi = mid; else lo = mid;
    }
    eout[76 - t] = 0.5f * (lo + hi);  // descending
  }
}

// ---------------- launch ----------------
extern "C" void kernel_launch(void* const* d_in, const int* in_sizes, int n_in,
                              void* d_out, int out_size, void* d_ws, size_t ws_size,
                              hipStream_t stream) {
  const float* omega  = (const float*)d_in[0];
  const float* Phi    = (const float*)d_in[1];
  const float* metric = (const float*)d_in[2];
  for (int q = 0; q < n_in && q < 3; ++q) {
    if (in_sizes[q] == SZ_OMEGA)       omega  = (const float*)d_in[q];
    else if (in_sizes[q] == SZ_PHI)    Phi    = (const float*)d_in[q];
    else if (in_sizes[q] == SZ_METRIC) metric = (const float*)d_in[q];
  }

  float* out = (float*)d_out;

  // All scratch inside d_out (d_ws unused):
  //   out[0 .. Y_SIZE)            : Sraw accumulator -> finalized Y
  //   out[VOLOFF .. VOLOFF+4096)  : vol[n] (temp, overwritten by gram's M)
  //   out[VSUM]                   : volsum (temp, overwritten by gram's M)
  hipMemsetAsync(d_out, 0, (size_t)out_size * sizeof(float), stream);

  hipLaunchKernelGGL(vol_kernel, dim3(NBATCH / 256), dim3(256), 0, stream, metric, out);
  hipLaunchKernelGGL(contract_kernel, dim3(GRID_B), dim3(BLK), 0, stream,
                     omega, Phi, out);
  hipLaunchKernelGGL(finalize_y, dim3((NPAIR * NK + 255) / 256), dim3(256), 0, stream,
                     out);
  hipLaunchKernelGGL(gram_kernel, dim3((M_SIZE + 255) / 256), dim3(256), 0, stream,
                     out, out + Y_SIZE);
  hipLaunchKernelGGL(eig_kernel, dim3(1), dim3(EIGT), 0, stream,
                     out + Y_SIZE, out + Y_SIZE + M_SIZE);
}